// Round 1
// baseline (153.375 us; speedup 1.0000x reference)
//
#include <hip/hip_runtime.h>

#define NQ  10
#define DIM (1 << NQ)   // 1024
#define BLK 256

__global__ __launch_bounds__(BLK) void qnn_kernel(
    const float* __restrict__ x,      // (B, NQ)
    const float* __restrict__ fminp,  // (1,)
    const float* __restrict__ qw,     // (69,)
    const float* __restrict__ dk,     // (NQ,)
    const float* __restrict__ db,     // (1,)
    float* __restrict__ out,          // (B,)
    int B)
{
    __shared__ float re[DIM];
    __shared__ float im[DIM];
    __shared__ float red[BLK / 64];

    const int b   = blockIdx.x;
    const int tid = threadIdx.x;
    if (b >= B) return;

    // |0...0>
    for (int i = tid; i < DIM; i += BLK) { re[i] = 0.0f; im[i] = 0.0f; }
    if (tid == 0) re[0] = 1.0f;
    __syncthreads();

    const float fm = fminp[0];

    // generic single-qubit gate: psi' = M psi on qubit q (bit p = NQ-1-q)
    auto apply1 = [&](int q, float m00r, float m00i, float m01r, float m01i,
                             float m10r, float m10i, float m11r, float m11i) {
        const int p = NQ - 1 - q;
        #pragma unroll
        for (int it = 0; it < (DIM / 2) / BLK; ++it) {
            const int t  = tid + it * BLK;
            const int i0 = ((t >> p) << (p + 1)) | (t & ((1 << p) - 1));
            const int i1 = i0 | (1 << p);
            const float ar = re[i0], ai = im[i0];
            const float br = re[i1], bi = im[i1];
            re[i0] = m00r * ar - m00i * ai + m01r * br - m01i * bi;
            im[i0] = m00r * ai + m00i * ar + m01r * bi + m01i * br;
            re[i1] = m10r * ar - m10i * ai + m11r * br - m11i * bi;
            im[i1] = m10r * ai + m10i * ar + m11r * bi + m11i * br;
        }
        __syncthreads();
    };

    // tensorcircuit r gate: exp(-i t n.sigma), n=(sin a cos p, sin a sin p, cos a)
    auto applyR = [&](int q, float t, float ph, float a) {
        float st, ct, sa, ca, sp, cp;
        sincosf(t,  &st, &ct);
        sincosf(a,  &sa, &ca);
        sincosf(ph, &sp, &cp);
        const float ss = st * sa;
        // m00 = (ct, -st*ca); m01 = (-ss*sp, -ss*cp); m10 = (ss*sp, -ss*cp); m11 = (ct, st*ca)
        apply1(q, ct, -st * ca, -ss * sp, -ss * cp, ss * sp, -ss * cp, ct, st * ca);
    };

    // exp(-i th X(x)X) on qubits (j, j+1): pairs a <-> a^mask, new_a = c*a - i*s*b
    auto applyXX = [&](int j, float th) {
        float s, c;
        sincosf(th, &s, &c);
        const int p1   = NQ - 1 - j;           // higher bit (qubit j)
        const int mask = (1 << p1) | (1 << (p1 - 1));
        #pragma unroll
        for (int it = 0; it < (DIM / 2) / BLK; ++it) {
            const int t  = tid + it * BLK;
            const int i0 = ((t >> p1) << (p1 + 1)) | (t & ((1 << p1) - 1)); // bit p1 == 0
            const int i1 = i0 ^ mask;
            const float ar = re[i0], ai = im[i0];
            const float br = re[i1], bi = im[i1];
            re[i0] = c * ar + s * bi;
            im[i0] = c * ai - s * br;
            re[i1] = c * br + s * ai;
            im[i1] = c * bi - s * ar;
        }
        __syncthreads();
    };

    // ---- circuit (NF = LD = 1) ----
    // RX data-encoding layer: exp(-i th/2 X)
    for (int j = 0; j < NQ; ++j) {
        const float half = 0.5f * x[b * NQ + j] * fm;
        float s, c;
        sincosf(half, &s, &c);
        apply1(j, c, 0.0f, 0.0f, -s, 0.0f, -s, c, 0.0f);
    }
    // trainable R layer: weights[0,0,j,{0,1,2}] = qw[3j .. 3j+2]
    for (int j = 0; j < NQ; ++j)
        applyR(j, qw[3 * j + 0], qw[3 * j + 1], qw[3 * j + 2]);
    // entangling RXX chain: ent_w[j] = qw[30 + j]
    for (int j = 0; j < NQ - 1; ++j)
        applyXX(j, qw[30 + j]);
    // final R layer: final_r[j,{0,1,2}] = qw[39 + 3j ...]
    for (int j = 0; j < NQ; ++j)
        applyR(j, qw[39 + 3 * j + 0], qw[39 + 3 * j + 1], qw[39 + 3 * j + 2]);

    // ---- fused <Z_j> @ dense_kernel + bias ----
    float dkr[NQ];
    #pragma unroll
    for (int j = 0; j < NQ; ++j) dkr[j] = dk[j];

    float acc = 0.0f;
    #pragma unroll
    for (int it = 0; it < DIM / BLK; ++it) {
        const int i = tid + it * BLK;
        const float pr = re[i] * re[i] + im[i] * im[i];
        float w = 0.0f;
        #pragma unroll
        for (int j = 0; j < NQ; ++j)
            w += ((i >> (NQ - 1 - j)) & 1) ? -dkr[j] : dkr[j];
        acc += pr * w;
    }
    #pragma unroll
    for (int off = 32; off; off >>= 1) acc += __shfl_down(acc, off, 64);
    if ((tid & 63) == 0) red[tid >> 6] = acc;
    __syncthreads();
    if (tid == 0) out[b] = red[0] + red[1] + red[2] + red[3] + db[0];
}

extern "C" void kernel_launch(void* const* d_in, const int* in_sizes, int n_in,
                              void* d_out, int out_size, void* d_ws, size_t ws_size,
                              hipStream_t stream) {
    const float* x    = (const float*)d_in[0];
    const float* fmin = (const float*)d_in[1];
    const float* qw   = (const float*)d_in[2];
    const float* dk   = (const float*)d_in[3];
    const float* db   = (const float*)d_in[4];
    float* out = (float*)d_out;
    const int B = in_sizes[0] / NQ;   // 8192
    qnn_kernel<<<B, BLK, 0, stream>>>(x, fmin, qw, dk, db, out, B);
}

// Round 2
// 72.817 us; speedup vs baseline: 2.1063x; 2.1063x over previous
//
#include <hip/hip_runtime.h>

#define NQ  10
#define BLK 256   // 4 waves/block, 1 circuit per wave

// ============================================================================
// Coefficient table in d_ws (178 floats):
//   [0..79]    R layer, gate j: 8 floats m00r,m00i,m01r,m01i,m10r,m10i,m11r,m11i
//   [80..97]   RXX j: c, s
//   [98..177]  final R, gate j: 8 floats
// ============================================================================
__global__ void coef_kernel(const float* __restrict__ qw, float* __restrict__ cf) {
    const int t = threadIdx.x;
    if (t < 10) {
        const float th = qw[3*t], ph = qw[3*t+1], al = qw[3*t+2];
        float st, ct, sa, ca, sp, cp;
        sincosf(th, &st, &ct); sincosf(al, &sa, &ca); sincosf(ph, &sp, &cp);
        const float ss = st * sa;
        float* m = cf + 8*t;
        m[0]=ct; m[1]=-st*ca; m[2]=-ss*sp; m[3]=-ss*cp;
        m[4]=ss*sp; m[5]=-ss*cp; m[6]=ct; m[7]=st*ca;
    } else if (t < 19) {
        const int j = t - 10;
        float s, c; sincosf(qw[30 + j], &s, &c);
        cf[80 + 2*j] = c; cf[80 + 2*j + 1] = s;
    } else if (t < 29) {
        const int j = t - 19;
        const float th = qw[39+3*j], ph = qw[39+3*j+1], al = qw[39+3*j+2];
        float st, ct, sa, ca, sp, cp;
        sincosf(th, &st, &ct); sincosf(al, &sa, &ca); sincosf(ph, &sp, &cp);
        const float ss = st * sa;
        float* m = cf + 98 + 8*j;
        m[0]=ct; m[1]=-st*ca; m[2]=-ss*sp; m[3]=-ss*cp;
        m[4]=ss*sp; m[5]=-ss*cp; m[6]=ct; m[7]=st*ca;
    }
}

// ============================================================================
// Gate primitives. State: 16 complex amps/lane; global index = (lane<<4)|r.
// Lane bits = index bits [9:4], register bits = [3:0]. All indices static.
// ============================================================================

// generic 1-qubit gate on a LANE bit; cs/co are this lane's (row-selected)
// matrix coefficients: out = cs*self + co*other
template<int MASK>
__device__ __forceinline__ void gate1_lane(float (&sr)[16], float (&si)[16],
                                           float csr, float csi, float cor, float coi) {
    #pragma unroll
    for (int r = 0; r < 16; ++r) {
        const float orr = __shfl_xor(sr[r], MASK, 64);
        const float oi  = __shfl_xor(si[r], MASK, 64);
        const float nr = csr*sr[r] - csi*si[r] + cor*orr - coi*oi;
        const float ni = csr*si[r] + csi*sr[r] + cor*oi  + coi*orr;
        sr[r] = nr; si[r] = ni;
    }
}

// generic 1-qubit gate on a REGISTER bit P
template<int P>
__device__ __forceinline__ void gate1_reg(float (&sr)[16], float (&si)[16],
        float m00r, float m00i, float m01r, float m01i,
        float m10r, float m10i, float m11r, float m11i) {
    #pragma unroll
    for (int t = 0; t < 8; ++t) {
        const int r0 = ((t >> P) << (P + 1)) | (t & ((1 << P) - 1));
        const int r1 = r0 | (1 << P);
        const float ar = sr[r0], ai = si[r0], br = sr[r1], bi = si[r1];
        sr[r0] = m00r*ar - m00i*ai + m01r*br - m01i*bi;
        si[r0] = m00r*ai + m00i*ar + m01r*bi + m01i*br;
        sr[r1] = m10r*ar - m10i*ai + m11r*br - m11i*bi;
        si[r1] = m10r*ai + m10i*ar + m11r*bi + m11i*br;
    }
}

// XX-like symmetric gate (RX and RXX): out = c*self - i*s*other, LANE mask
template<int MASK>
__device__ __forceinline__ void xx_lane(float (&sr)[16], float (&si)[16], float c, float s) {
    #pragma unroll
    for (int r = 0; r < 16; ++r) {
        const float orr = __shfl_xor(sr[r], MASK, 64);
        const float oi  = __shfl_xor(si[r], MASK, 64);
        const float nr = c*sr[r] + s*oi;
        const float ni = c*si[r] - s*orr;
        sr[r] = nr; si[r] = ni;
    }
}

// XX-like symmetric gate, REGISTER mask M (1 or 2 bits)
template<int M>
__device__ __forceinline__ void xx_reg(float (&sr)[16], float (&si)[16], float c, float s) {
    constexpr int H = (M & 8) ? 3 : (M & 4) ? 2 : (M & 2) ? 1 : 0;   // high bit of M
    #pragma unroll
    for (int t = 0; t < 8; ++t) {
        const int r0 = ((t >> H) << (H + 1)) | (t & ((1 << H) - 1));  // bit H == 0
        const int r1 = r0 ^ M;
        const float ar = sr[r0], ai = si[r0], br = sr[r1], bi = si[r1];
        sr[r0] = c*ar + s*bi;
        si[r0] = c*ai - s*br;
        sr[r1] = c*br + s*ai;
        si[r1] = c*bi - s*ar;
    }
}

// RXX on (lane bit 0, register bit 3): partner = (lane^1, r^8)
__device__ __forceinline__ void xx_mixed(float (&sr)[16], float (&si)[16], float c, float s) {
    #pragma unroll
    for (int r0 = 0; r0 < 8; ++r0) {
        const int r1 = r0 + 8;
        const float o0r = __shfl_xor(sr[r1], 1, 64);
        const float o0i = __shfl_xor(si[r1], 1, 64);
        const float o1r = __shfl_xor(sr[r0], 1, 64);
        const float o1i = __shfl_xor(si[r0], 1, 64);
        const float n0r = c*sr[r0] + s*o0i;
        const float n0i = c*si[r0] - s*o0r;
        const float n1r = c*sr[r1] + s*o1i;
        const float n1i = c*si[r1] - s*o1r;
        sr[r0] = n0r; si[r0] = n0i;
        sr[r1] = n1r; si[r1] = n1i;
    }
}

// R gate from table, LANE bit LB. m00r==m11r, m01i==m10i; only two sign-selects.
template<int LB>
__device__ __forceinline__ void r_lane_tab(float (&sr)[16], float (&si)[16],
                                           int lane, const float* __restrict__ m) {
    const bool hi = (lane >> LB) & 1;
    const float csr = m[0];
    const float csi = hi ? m[7] : m[1];
    const float cor = hi ? m[4] : m[2];
    const float coi = m[3];
    gate1_lane<(1 << LB)>(sr, si, csr, csi, cor, coi);
}

template<int P>
__device__ __forceinline__ void r_reg_tab(float (&sr)[16], float (&si)[16],
                                          const float* __restrict__ m) {
    gate1_reg<P>(sr, si, m[0], m[1], m[2], m[3], m[4], m[5], m[6], m[7]);
}

// ============================================================================
__global__ __launch_bounds__(BLK) void qnn_kernel(
    const float* __restrict__ x,      // (B, NQ)
    const float* __restrict__ fminp,  // (1,)
    const float* __restrict__ cf,     // coefficient table (d_ws)
    const float* __restrict__ dk,     // (NQ,)
    const float* __restrict__ db,     // (1,)
    float* __restrict__ out,          // (B,)
    int B)
{
    const int lane = threadIdx.x & 63;
    const int b = blockIdx.x * (BLK / 64) + (threadIdx.x >> 6);
    if (b >= B) return;

    const float fm = fminp[0];

    // |0...0>: global index 0 -> lane 0, slot 0
    float sr[16], si[16];
    #pragma unroll
    for (int r = 0; r < 16; ++r) { sr[r] = 0.0f; si[r] = 0.0f; }
    if (lane == 0) sr[0] = 1.0f;

    // ---- RX encoding layer: exp(-i th/2 X), th = x*fm ----
    {
        float s, c;
        sincosf(0.5f * fm * x[b*NQ + 0], &s, &c); xx_lane<32>(sr, si, c, s);
        sincosf(0.5f * fm * x[b*NQ + 1], &s, &c); xx_lane<16>(sr, si, c, s);
        sincosf(0.5f * fm * x[b*NQ + 2], &s, &c); xx_lane< 8>(sr, si, c, s);
        sincosf(0.5f * fm * x[b*NQ + 3], &s, &c); xx_lane< 4>(sr, si, c, s);
        sincosf(0.5f * fm * x[b*NQ + 4], &s, &c); xx_lane< 2>(sr, si, c, s);
        sincosf(0.5f * fm * x[b*NQ + 5], &s, &c); xx_lane< 1>(sr, si, c, s);
        sincosf(0.5f * fm * x[b*NQ + 6], &s, &c); xx_reg < 8>(sr, si, c, s);
        sincosf(0.5f * fm * x[b*NQ + 7], &s, &c); xx_reg < 4>(sr, si, c, s);
        sincosf(0.5f * fm * x[b*NQ + 8], &s, &c); xx_reg < 2>(sr, si, c, s);
        sincosf(0.5f * fm * x[b*NQ + 9], &s, &c); xx_reg < 1>(sr, si, c, s);
    }

    // ---- trainable R layer ----
    r_lane_tab<5>(sr, si, lane, cf +  0);
    r_lane_tab<4>(sr, si, lane, cf +  8);
    r_lane_tab<3>(sr, si, lane, cf + 16);
    r_lane_tab<2>(sr, si, lane, cf + 24);
    r_lane_tab<1>(sr, si, lane, cf + 32);
    r_lane_tab<0>(sr, si, lane, cf + 40);
    r_reg_tab <3>(sr, si, cf + 48);
    r_reg_tab <2>(sr, si, cf + 56);
    r_reg_tab <1>(sr, si, cf + 64);
    r_reg_tab <0>(sr, si, cf + 72);

    // ---- entangling RXX chain ----
    xx_lane<48>(sr, si, cf[80], cf[81]);   // j=0: bits (9,8)
    xx_lane<24>(sr, si, cf[82], cf[83]);   // j=1
    xx_lane<12>(sr, si, cf[84], cf[85]);   // j=2
    xx_lane< 6>(sr, si, cf[86], cf[87]);   // j=3
    xx_lane< 3>(sr, si, cf[88], cf[89]);   // j=4
    xx_mixed   (sr, si, cf[90], cf[91]);   // j=5: bits (4,3) = lane0 x reg3
    xx_reg <12>(sr, si, cf[92], cf[93]);   // j=6
    xx_reg < 6>(sr, si, cf[94], cf[95]);   // j=7
    xx_reg < 3>(sr, si, cf[96], cf[97]);   // j=8

    // ---- final R layer ----
    r_lane_tab<5>(sr, si, lane, cf +  98);
    r_lane_tab<4>(sr, si, lane, cf + 106);
    r_lane_tab<3>(sr, si, lane, cf + 114);
    r_lane_tab<2>(sr, si, lane, cf + 122);
    r_lane_tab<1>(sr, si, lane, cf + 130);
    r_lane_tab<0>(sr, si, lane, cf + 138);
    r_reg_tab <3>(sr, si, cf + 146);
    r_reg_tab <2>(sr, si, cf + 154);
    r_reg_tab <1>(sr, si, cf + 162);
    r_reg_tab <0>(sr, si, cf + 170);

    // ---- fused <Z_j> @ dense_kernel + bias ----
    // weight(idx) = sum_j sign_j(idx) * dk[j]; split lane-bit / reg-bit parts
    float wlane = 0.0f;
    #pragma unroll
    for (int j = 0; j < 6; ++j)
        wlane += ((lane >> (5 - j)) & 1) ? -dk[j] : dk[j];

    float acc = 0.0f;
    #pragma unroll
    for (int r = 0; r < 16; ++r) {
        const float p = sr[r]*sr[r] + si[r]*si[r];
        float w = wlane;
        #pragma unroll
        for (int j = 6; j < 10; ++j)
            w += ((r >> (9 - j)) & 1) ? -dk[j] : dk[j];
        acc += p * w;
    }
    #pragma unroll
    for (int off = 32; off; off >>= 1) acc += __shfl_xor(acc, off, 64);
    if (lane == 0) out[b] = acc + db[0];
}

extern "C" void kernel_launch(void* const* d_in, const int* in_sizes, int n_in,
                              void* d_out, int out_size, void* d_ws, size_t ws_size,
                              hipStream_t stream) {
    const float* x    = (const float*)d_in[0];
    const float* fmin = (const float*)d_in[1];
    const float* qw   = (const float*)d_in[2];
    const float* dk   = (const float*)d_in[3];
    const float* db   = (const float*)d_in[4];
    float* out = (float*)d_out;
    float* cf  = (float*)d_ws;            // 178 floats
    const int B = in_sizes[0] / NQ;       // 8192

    coef_kernel<<<1, 64, 0, stream>>>(qw, cf);
    qnn_kernel<<<(B + BLK/64 - 1) / (BLK/64), BLK, 0, stream>>>(
        x, fmin, cf, dk, db, out, B);
}

// Round 3
// 31.150 us; speedup vs baseline: 4.9237x; 2.3376x over previous
//
#include <hip/hip_runtime.h>

#define NQ  10
#define BLK 256   // 4 waves/block, 1 circuit per wave

// ----------------------------------------------------------------------------
// cf layout (floats):
//  [0..79]    P_j = H * R_j            (10 qubits x 8: P00r,P00i,P01r,P01i,P10r,P10i,P11r,P11i)
//  [80..143]  T5[32] complex           (phase products for lane-pair couplings th0..th4)
//  [144..159] E678[8] complex          (phase products for reg-pair couplings th6..th8)
//  [160..161] (cos th5, sin th5)       (mixed lane/reg coupling)
//  [176..215] meas[10] x {g, er, ei, pad}:
//             g  = dk_j * gamma_j                    (all j)
//             j<6 : er = dk_j*delta_r, ei = dk_j*delta_i
//             j>=6: er = 2*dk_j*delta_r, ei = -2*dk_j*delta_i
// ----------------------------------------------------------------------------
__global__ void coef_kernel(const float* __restrict__ qw,
                            const float* __restrict__ dk,
                            float* __restrict__ cf) {
    const int t = threadIdx.x;
    const float is2 = 0.70710678118654752440f;
    if (t < 10) {
        // trainable R layer gate j = t
        const float th = qw[3*t], ph = qw[3*t+1], al = qw[3*t+2];
        float st, ct, sa, ca, sp, cp;
        sincosf(th, &st, &ct); sincosf(al, &sa, &ca); sincosf(ph, &sp, &cp);
        const float ss = st * sa;
        const float m00r = ct,    m00i = -st*ca, m01r = -ss*sp, m01i = -ss*cp;
        const float m10r = ss*sp, m10i = -ss*cp, m11r = ct,     m11i =  st*ca;
        // P = H * R  (rows mixed)
        float* p = cf + 8*t;
        p[0] = (m00r+m10r)*is2; p[1] = (m00i+m10i)*is2;
        p[2] = (m01r+m11r)*is2; p[3] = (m01i+m11i)*is2;
        p[4] = (m00r-m10r)*is2; p[5] = (m00i-m10i)*is2;
        p[6] = (m01r-m11r)*is2; p[7] = (m01i-m11i)*is2;
    } else if (t < 20) {
        // final R layer gate j; G = Rf * H (cols mixed); observable A = G^dag Z G
        const int j = t - 10;
        const float th = qw[39+3*j], ph = qw[39+3*j+1], al = qw[39+3*j+2];
        float st, ct, sa, ca, sp, cp;
        sincosf(th, &st, &ct); sincosf(al, &sa, &ca); sincosf(ph, &sp, &cp);
        const float ss = st * sa;
        const float m00r = ct,    m00i = -st*ca, m01r = -ss*sp, m01i = -ss*cp;
        const float m10r = ss*sp, m10i = -ss*cp, m11r = ct,     m11i =  st*ca;
        const float G00r=(m00r+m01r)*is2, G00i=(m00i+m01i)*is2;
        const float G01r=(m00r-m01r)*is2, G01i=(m00i-m01i)*is2;
        const float G10r=(m10r+m11r)*is2, G10i=(m10i+m11i)*is2;
        const float G11r=(m10r-m11r)*is2, G11i=(m10i-m11i)*is2;
        const float gam = G00r*G00r + G00i*G00i - G10r*G10r - G10i*G10i;
        // delta = conj(G00)*G01 - conj(G10)*G11
        const float dr = G00r*G01r + G00i*G01i - (G10r*G11r + G10i*G11i);
        const float di = G00r*G01i - G00i*G01r - (G10r*G11i - G10i*G11r);
        const float dkj = dk[j];
        float* q = cf + 176 + 4*j;
        q[0] = dkj * gam;
        if (j < 6) { q[1] = dkj*dr;      q[2] = dkj*di;       }
        else       { q[1] = 2.f*dkj*dr;  q[2] = -2.f*dkj*di;  }
        q[3] = 0.f;
    } else if (t < 52) {
        // T5[v]: bit m of v = XOR of lane bits (m, m+1) = qubit pair (4-m, 5-m) -> theta_{4-m}
        const int v = t - 20;
        float pr = 1.f, pi = 0.f;
        for (int m = 0; m < 5; ++m) {
            float s, c; sincosf(qw[30 + 4 - m], &s, &c);
            const float fi = ((v >> m) & 1) ? s : -s;   // equal bits -> e^{-i th}
            const float nr = pr*c - pi*fi, ni = pr*fi + pi*c;
            pr = nr; pi = ni;
        }
        cf[80 + 2*v] = pr; cf[80 + 2*v + 1] = pi;
    } else if (t < 60) {
        // E678[e]: bit n of e = XOR of reg bits (n, n+1) -> theta_{8-n}
        const int e = t - 52;
        float pr = 1.f, pi = 0.f;
        for (int n = 0; n < 3; ++n) {
            float s, c; sincosf(qw[30 + 8 - n], &s, &c);
            const float fi = ((e >> n) & 1) ? s : -s;
            const float nr = pr*c - pi*fi, ni = pr*fi + pi*c;
            pr = nr; pi = ni;
        }
        cf[144 + 2*e] = pr; cf[144 + 2*e + 1] = pi;
    } else if (t == 60) {
        float s, c; sincosf(qw[35], &s, &c);   // theta_5
        cf[160] = c; cf[161] = s;
    }
}

// ----------------------------------------------------------------------------
__global__ __launch_bounds__(BLK) void qnn_kernel(
    const float* __restrict__ x,      // (B, NQ)
    const float* __restrict__ fminp,  // (1,)
    const float* __restrict__ cf,     // coefficient tables (d_ws)
    const float* __restrict__ db,     // (1,)
    float* __restrict__ out,          // (B,)
    int B)
{
    const int lane = threadIdx.x & 63;
    const int b = blockIdx.x * (BLK/64) + (threadIdx.x >> 6);
    if (b >= B) return;

    const float fm = fminp[0];
    const float* xb = x + b*NQ;

    // ---- lane-uniform scalar W = T5[v] * prod_{j=0..5} w_j[lane bit] ----
    const int v = (lane ^ (lane >> 1)) & 31;
    float Wr = cf[80 + 2*v], Wi = cf[81 + 2*v];
    #pragma unroll
    for (int j = 0; j < 6; ++j) {
        const float a = 0.5f * fm * xb[j];
        const float s = __sinf(a), c = __cosf(a);
        const float* p = cf + 8*j;
        const bool hi = (lane >> (5 - j)) & 1;
        const float ar = hi ? p[4] : p[0], ai = hi ? p[5] : p[1];
        const float br = hi ? p[6] : p[2], bi = hi ? p[7] : p[3];
        // w = P.row * (c, -i s):  wr = ar*c + bi*s ; wi = ai*c - br*s
        const float wr = ar*c + bi*s;
        const float wi = ai*c - br*s;
        const float nr = Wr*wr - Wi*wi;
        const float ni = Wr*wi + Wi*wr;
        Wr = nr; Wi = ni;
    }

    // ---- reg-qubit (6..9) 2-vectors ----
    float wr_[4][2], wi_[4][2];
    #pragma unroll
    for (int k = 0; k < 4; ++k) {
        const float a = 0.5f * fm * xb[6 + k];
        const float s = __sinf(a), c = __cosf(a);
        const float* p = cf + 8*(6 + k);
        wr_[k][0] = p[0]*c + p[3]*s;  wi_[k][0] = p[1]*c - p[2]*s;
        wr_[k][1] = p[4]*c + p[7]*s;  wi_[k][1] = p[5]*c - p[6]*s;
    }

    // ---- product tree -> psi[16] (reg bits b3..b0 = qubits 6..9) ----
    float pr16[16], pi16[16];
    {
        float Ar[2], Ai[2], Br[4], Bi[4], Cr[8], Ci[8];
        #pragma unroll
        for (int i = 0; i < 2; ++i) {
            Ar[i] = Wr*wr_[0][i] - Wi*wi_[0][i];
            Ai[i] = Wr*wi_[0][i] + Wi*wr_[0][i];
        }
        #pragma unroll
        for (int i = 0; i < 4; ++i) { const int h = i>>1, l = i&1;
            Br[i] = Ar[h]*wr_[1][l] - Ai[h]*wi_[1][l];
            Bi[i] = Ar[h]*wi_[1][l] + Ai[h]*wr_[1][l]; }
        #pragma unroll
        for (int i = 0; i < 8; ++i) { const int h = i>>1, l = i&1;
            Cr[i] = Br[h]*wr_[2][l] - Bi[h]*wi_[2][l];
            Ci[i] = Br[h]*wi_[2][l] + Bi[h]*wr_[2][l]; }
        #pragma unroll
        for (int r = 0; r < 16; ++r) { const int h = r>>1, l = r&1;
            pr16[r] = Cr[h]*wr_[3][l] - Ci[h]*wi_[3][l];
            pi16[r] = Cr[h]*wi_[3][l] + Ci[h]*wr_[3][l]; }
    }

    // ---- diagonal entangler phases (zero shuffles) ----
    const float c5 = cf[160], s5 = cf[161];
    const float s5a = (lane & 1) ? s5 : -s5;   // r_b3=0: bits equal iff lane_b0==0 -> -s5
    #pragma unroll
    for (int r = 0; r < 16; ++r) {
        const int e = (r ^ (r >> 1)) & 7;      // compile-time per r
        const float er_ = cf[144 + 2*e], ei_ = cf[145 + 2*e];
        const float nr = pr16[r]*er_ - pi16[r]*ei_;
        const float ni = pr16[r]*ei_ + pi16[r]*er_;
        const float sx = (r & 8) ? -s5a : s5a;
        pr16[r] = nr*c5 - ni*sx;
        pi16[r] = nr*sx + ni*c5;
    }

    // ---- measurement: out = sum_j dk_j <G^dag Z G>_j ----
    // gamma part: weighted probability sum
    const float g0 = cf[176], g1 = cf[180], g2 = cf[184], g3 = cf[188], g4 = cf[192];
    const float g5 = cf[196], g6 = cf[200], g7 = cf[204], g8 = cf[208], g9 = cf[212];
    float wl = ((lane & 32) ? -g0 : g0) + ((lane & 16) ? -g1 : g1)
             + ((lane &  8) ? -g2 : g2) + ((lane &  4) ? -g3 : g3)
             + ((lane &  2) ? -g4 : g4) + ((lane &  1) ? -g5 : g5);
    float acc = 0.f;
    #pragma unroll
    for (int r = 0; r < 16; ++r) {
        const float p = pr16[r]*pr16[r] + pi16[r]*pi16[r];
        const float w = wl + ((r & 8) ? -g6 : g6) + ((r & 4) ? -g7 : g7)
                           + ((r & 2) ? -g8 : g8) + ((r & 1) ? -g9 : g9);
        acc += p * w;
    }
    // delta part, reg qubits 6..9 (er,ei pre-scaled & pre-negated in cf)
    #pragma unroll
    for (int k = 0; k < 4; ++k) {
        const int mask = 8 >> k;
        const float er = cf[201 + 4*k], ei = cf[202 + 4*k];
        #pragma unroll
        for (int r0 = 0; r0 < 16; ++r0) {
            if (r0 & mask) continue;
            const int r1 = r0 | mask;
            const float tr = pr16[r0]*pr16[r1] + pi16[r0]*pi16[r1];
            const float ti = pr16[r0]*pi16[r1] - pi16[r0]*pr16[r1];
            acc += er*tr + ei*ti;
        }
    }
    // delta part, lane qubits 0..5 (pairs counted twice across wave -> er,ei unscaled)
    #pragma unroll
    for (int j = 0; j < 6; ++j) {
        const int M = 32 >> j;
        const float er = cf[177 + 4*j], ei = cf[178 + 4*j];
        const float sei = (lane & M) ? ei : -ei;
        #pragma unroll
        for (int r = 0; r < 16; ++r) {
            const float br = __shfl_xor(pr16[r], M, 64);
            const float bi = __shfl_xor(pi16[r], M, 64);
            acc += er*(pr16[r]*br + pi16[r]*bi) + sei*(pr16[r]*bi - pi16[r]*br);
        }
    }

    #pragma unroll
    for (int off = 32; off; off >>= 1) acc += __shfl_xor(acc, off, 64);
    if (lane == 0) out[b] = acc + db[0];
}

extern "C" void kernel_launch(void* const* d_in, const int* in_sizes, int n_in,
                              void* d_out, int out_size, void* d_ws, size_t ws_size,
                              hipStream_t stream) {
    const float* x    = (const float*)d_in[0];
    const float* fmin = (const float*)d_in[1];
    const float* qw   = (const float*)d_in[2];
    const float* dk   = (const float*)d_in[3];
    const float* db   = (const float*)d_in[4];
    float* out = (float*)d_out;
    float* cf  = (float*)d_ws;            // 216 floats
    const int B = in_sizes[0] / NQ;       // 8192

    coef_kernel<<<1, 64, 0, stream>>>(qw, dk, cf);
    qnn_kernel<<<(B + BLK/64 - 1) / (BLK/64), BLK, 0, stream>>>(
        x, fmin, cf, db, out, B);
}

// Round 4
// 9.725 us; speedup vs baseline: 15.7715x; 3.2032x over previous
//
#include <hip/hip_runtime.h>

#define NQ  10
#define BLK 256

// Closed form:
//   psi = (⊗_j G_j) · D · (⊗_j w_j)
//     w_j = H · R_j · rx(x_j*fm) |0>          (2-vector)
//     D   = diag Π_e e^{-i th_e z_e z_{e+1}}  (RXX chain in X basis)
//     G_j = Rf_j · H
//   <Z_j> = gam_j * d_j + 2 Re[ del_j * conj(w_j0) w_j1 * L_j * R_j ]
//     d_j = |w_j0|^2 - |w_j1|^2
//     L_j = cos(2 th_{j-1}) + i sin(2 th_{j-1}) d_{j-1}   (1 for j=0)
//     R_j = cos(2 th_j)     + i sin(2 th_j)     d_{j+1}   (1 for j=9)
//   out  = sum_j dk_j <Z_j> + bias
__global__ __launch_bounds__(BLK) void qnn_kernel(
    const float* __restrict__ x,      // (B, NQ)
    const float* __restrict__ fminp,  // (1,)
    const float* __restrict__ qw,     // (69,)
    const float* __restrict__ dk,     // (NQ,)
    const float* __restrict__ db,     // (1,)
    float* __restrict__ out,          // (B,)
    int B)
{
    __shared__ float P[80];                    // P_j = H * R_j (8 floats/qubit)
    __shared__ float g[10], dr_[10], di_[10];  // dk_j*gamma, dk_j*delta
    __shared__ float Tc[11], Ts[11];           // padded edge table cos/sin(2 th)

    const int t = threadIdx.x;
    const float is2 = 0.70710678118654752440f;

    if (t < 10) {
        // trainable R layer gate j = t ; P = H * R (rows mixed)
        const float th = qw[3*t], ph = qw[3*t+1], al = qw[3*t+2];
        float st, ct, sa, ca, sp, cp;
        sincosf(th, &st, &ct); sincosf(al, &sa, &ca); sincosf(ph, &sp, &cp);
        const float ss = st * sa;
        const float m00r = ct,    m00i = -st*ca, m01r = -ss*sp, m01i = -ss*cp;
        const float m10r = ss*sp, m10i = -ss*cp, m11r = ct,     m11i =  st*ca;
        float* p = P + 8*t;
        p[0] = (m00r+m10r)*is2; p[1] = (m00i+m10i)*is2;
        p[2] = (m01r+m11r)*is2; p[3] = (m01i+m11i)*is2;
        p[4] = (m00r-m10r)*is2; p[5] = (m00i-m10i)*is2;
        p[6] = (m01r-m11r)*is2; p[7] = (m01i-m11i)*is2;
    } else if (t < 20) {
        // final layer gate j ; G = Rf * H (cols mixed); A = G^dag Z G
        const int j = t - 10;
        const float th = qw[39+3*j], ph = qw[39+3*j+1], al = qw[39+3*j+2];
        float st, ct, sa, ca, sp, cp;
        sincosf(th, &st, &ct); sincosf(al, &sa, &ca); sincosf(ph, &sp, &cp);
        const float ss = st * sa;
        const float m00r = ct,    m00i = -st*ca, m01r = -ss*sp, m01i = -ss*cp;
        const float m10r = ss*sp, m10i = -ss*cp, m11r = ct,     m11i =  st*ca;
        const float G00r=(m00r+m01r)*is2, G00i=(m00i+m01i)*is2;
        const float G01r=(m00r-m01r)*is2, G01i=(m00i-m01i)*is2;
        const float G10r=(m10r+m11r)*is2, G10i=(m10i+m11i)*is2;
        const float G11r=(m10r-m11r)*is2, G11i=(m10i-m11i)*is2;
        const float gam = G00r*G00r + G00i*G00i - G10r*G10r - G10i*G10i;
        const float der = G00r*G01r + G00i*G01i - (G10r*G11r + G10i*G11i);
        const float dei = G00r*G01i - G00i*G01r - (G10r*G11i - G10i*G11r);
        const float dkj = dk[j];
        g[j]   = dkj * gam;
        dr_[j] = dkj * der;
        di_[j] = dkj * dei;
    } else if (t < 29) {
        const int k = t - 19;                       // k = 1..9, edge k-1
        float s, c; sincosf(2.0f * qw[30 + k - 1], &s, &c);
        Tc[k] = c; Ts[k] = s;
    } else if (t == 29) {
        Tc[0] = 1.0f; Ts[0] = 0.0f; Tc[10] = 1.0f; Ts[10] = 0.0f;
    }
    __syncthreads();

    const int b = blockIdx.x * BLK + t;
    if (b >= B) return;

    const float fm = fminp[0];
    const float* xb = x + b * NQ;

    float d[NQ], mr[NQ], mi[NQ];
    #pragma unroll
    for (int j = 0; j < NQ; ++j) {
        const float a = 0.5f * fm * xb[j];
        const float s = __sinf(a), c = __cosf(a);
        const float* p = P + 8*j;
        const float w0r = p[0]*c + p[3]*s;
        const float w0i = p[1]*c - p[2]*s;
        const float w1r = p[4]*c + p[7]*s;
        const float w1i = p[5]*c - p[6]*s;
        d[j]  = (w0r*w0r + w0i*w0i) - (w1r*w1r + w1i*w1i);
        mr[j] = w0r*w1r + w0i*w1i;
        mi[j] = w0r*w1i - w0i*w1r;
    }

    float acc = 0.0f;
    #pragma unroll
    for (int j = 0; j < NQ; ++j) {
        const float dL = (j == 0)      ? 0.0f : d[j == 0 ? 0 : j - 1];
        const float dR = (j == NQ - 1) ? 0.0f : d[j == NQ - 1 ? NQ - 1 : j + 1];
        const float Lr = Tc[j],     Li = Ts[j]     * dL;
        const float Rr = Tc[j + 1], Ri = Ts[j + 1] * dR;
        const float LRr = Lr*Rr - Li*Ri;
        const float LRi = Lr*Ri + Li*Rr;
        const float Yr = mr[j]*LRr - mi[j]*LRi;
        const float Yi = mr[j]*LRi + mi[j]*LRr;
        acc += g[j]*d[j] + 2.0f*(dr_[j]*Yr - di_[j]*Yi);
    }
    out[b] = acc + db[0];
}

extern "C" void kernel_launch(void* const* d_in, const int* in_sizes, int n_in,
                              void* d_out, int out_size, void* d_ws, size_t ws_size,
                              hipStream_t stream) {
    const float* x    = (const float*)d_in[0];
    const float* fmin = (const float*)d_in[1];
    const float* qw   = (const float*)d_in[2];
    const float* dk   = (const float*)d_in[3];
    const float* db   = (const float*)d_in[4];
    float* out = (float*)d_out;
    const int B = in_sizes[0] / NQ;   // 8192

    qnn_kernel<<<(B + BLK - 1) / BLK, BLK, 0, stream>>>(
        x, fmin, qw, dk, db, out, B);
}